// Round 1
// baseline (20490.002 us; speedup 1.0000x reference)
//
#include <hip/hip_runtime.h>
#include <hip/hip_fp16.h>

#define LL 5
#define H 1024
#define G 4096   // 4*H
#define T 128
#define BS 512

typedef _Float16 f16x8 __attribute__((ext_vector_type(8)));
typedef float f32x4 __attribute__((ext_vector_type(4)));

__device__ __forceinline__ float sigmoidf_(float x) { return 1.f / (1.f + __expf(-x)); }
__device__ __forceinline__ float tanhf_(float x) { return 2.f / (1.f + __expf(-2.f * x)) - 1.f; }

// ---- prelude: fp32 -> fp16 weight conversion (W_hh then W_ih_rest) ----
__global__ void k_convert(const float* __restrict__ Whf, const float* __restrict__ Wxf,
                          __half* __restrict__ Whb, __half* __restrict__ Wxb) {
  const long long n1 = (long long)LL * G * H / 4;       // float4 count for W_hh
  const long long n2 = (long long)(LL - 1) * G * H / 4; // float4 count for W_ih_rest
  long long i = (long long)blockIdx.x * blockDim.x + threadIdx.x;
  long long stride = (long long)gridDim.x * blockDim.x;
  for (long long v = i; v < n1 + n2; v += stride) {
    const float4* src; __half* dst; long long idx;
    if (v < n1) { src = (const float4*)Whf; dst = Whb; idx = v; }
    else        { src = (const float4*)Wxf; dst = Wxb; idx = v - n1; }
    float4 f = src[idx];
    __half h0 = __float2half(f.x), h1 = __float2half(f.y),
           h2 = __float2half(f.z), h3 = __float2half(f.w);
    ushort4 u;
    u.x = __half_as_ushort(h0); u.y = __half_as_ushort(h1);
    u.z = __half_as_ushort(h2); u.w = __half_as_ushort(h3);
    ((ushort4*)dst)[idx] = u;
  }
}

// ---- prelude: bias = b_ih + b_hh ; y = 0 ----
__global__ void k_bias_y(const float* __restrict__ bih, const float* __restrict__ bhh,
                         float* __restrict__ bias, float* __restrict__ y) {
  int i = blockIdx.x * blockDim.x + threadIdx.x;
  if (i < LL * G) bias[i] = bih[i] + bhh[i];
  if (i < BS) y[i] = 0.f;
}

// ---- prelude: h0 = c0 = tile(x) ----
__global__ void k_init(const float* __restrict__ x, __half* __restrict__ h0buf,
                       float* __restrict__ c) {
  int i = blockIdx.x * blockDim.x + threadIdx.x; // over BS*H
  if (i >= BS * H) return;
  float v = x[i];
  __half hb = __float2half(v);
  for (int l = 0; l < LL; l++) {
    h0buf[(long long)l * BS * H + i] = hb;
    c[(long long)l * BS * H + i] = v;
  }
}

// ---- fused GEMM + LSTM cell for one (t, l) ----
// Block tile: 64 batch rows x (32 j-cols x 4 gates). Grid (8, 32). 256 thr = 4 waves.
__global__ __launch_bounds__(256) void k_cell(
    const __half* __restrict__ Ah,   // h_prev[l]  [BS][H]
    const __half* __restrict__ Ax,   // h_cur[l-1] [BS][H] or null (l==0)
    const __half* __restrict__ Wh,   // [G][H] fp16
    const __half* __restrict__ Wx,   // [G][H] fp16 or null
    const float* __restrict__ bias,  // [G]
    const float* __restrict__ W0,    // W_ih0 [G] (l==0) or null
    const float* __restrict__ yprev, // [BS]  (l==0) or null
    float* __restrict__ c,           // [BS][H]
    __half* __restrict__ hout)       // [BS][H]
{
  __shared__ __half As[64][72];    // +8 pad: row stride 144B -> 2-way bank alias (free)
  __shared__ __half Bsh[128][72];
  __shared__ float gl[64][128];    // gates tile: [m][q*32+jj]

  const int t = threadIdx.x;
  const int m0 = blockIdx.x * 64;
  const int jb = blockIdx.y * 32;
  const int wave = t >> 6, lane = t & 63, quad = lane >> 4, col = lane & 15;
  const int wm = wave >> 1, wn = wave & 1; // wave tile: 32m x 64n

  f32x4 acc[2][4];
#pragma unroll
  for (int a = 0; a < 2; a++)
#pragma unroll
    for (int b = 0; b < 4; b++) acc[a][b] = (f32x4){0.f, 0.f, 0.f, 0.f};

  const int nIter = Ax ? 32 : 16; // K = 2048 (h-part then x-part) or 1024
  for (int it = 0; it < nIter; ++it) {
    const int kb = (it & 15) * 64;
    const __half* Asrc = (it < 16) ? Ah : Ax;
    const __half* Wsrc = (it < 16) ? Wh : Wx;
    // stage A: 64 rows x 64 k  (8KB), 2 x 16B per thread
#pragma unroll
    for (int s = 0; s < 2; s++) {
      int idx = s * 256 + t;
      int row = idx >> 3, cp = idx & 7;
      uint4 v = *(const uint4*)(Asrc + (long long)(m0 + row) * H + kb + cp * 8);
      *(uint4*)(&As[row][cp * 8]) = v;
    }
    // stage B: 128 rows x 64 k (16KB); row n -> gate q=n>>5, jj=n&31
#pragma unroll
    for (int s = 0; s < 4; s++) {
      int idx = s * 256 + t;
      int row = idx >> 3, cp = idx & 7;
      int grow = (row >> 5) * H + jb + (row & 31);
      uint4 v = *(const uint4*)(Wsrc + (long long)grow * H + kb + cp * 8);
      *(uint4*)(&Bsh[row][cp * 8]) = v;
    }
    __syncthreads();
#pragma unroll
    for (int ks = 0; ks < 2; ks++) {
      f16x8 af[2], bfr[4];
#pragma unroll
      for (int mt = 0; mt < 2; mt++)
        af[mt] = *(const f16x8*)(&As[wm * 32 + mt * 16 + col][ks * 32 + quad * 8]);
#pragma unroll
      for (int nt = 0; nt < 4; nt++)
        bfr[nt] = *(const f16x8*)(&Bsh[wn * 64 + nt * 16 + col][ks * 32 + quad * 8]);
#pragma unroll
      for (int mt = 0; mt < 2; mt++)
#pragma unroll
        for (int nt = 0; nt < 4; nt++)
          acc[mt][nt] = __builtin_amdgcn_mfma_f32_16x16x32_f16(af[mt], bfr[nt], acc[mt][nt], 0, 0, 0);
    }
    __syncthreads();
  }

  // gates -> LDS so each lane can gather its own (i,f,g,o)
#pragma unroll
  for (int mt = 0; mt < 2; mt++)
#pragma unroll
    for (int nt = 0; nt < 4; nt++)
#pragma unroll
      for (int r = 0; r < 4; r++)
        gl[wm * 32 + mt * 16 + quad * 4 + r][wn * 64 + nt * 16 + col] = acc[mt][nt][r];
  __syncthreads();

  // cell update: 64 rows x 32 j = 2048 elements, 8 per thread
#pragma unroll
  for (int s = 0; s < 8; s++) {
    int e = s * 256 + t;
    int row = e >> 5, jj = e & 31;
    int b = m0 + row, j = jb + jj;
    float gi = gl[row][jj], gf = gl[row][32 + jj], gg = gl[row][64 + jj], go = gl[row][96 + jj];
    if (W0) { // layer 0 rank-1 input term: y_prev[b] * W_ih0[gate]
      float yv = yprev[b];
      gi += yv * W0[j];
      gf += yv * W0[H + j];
      gg += yv * W0[2 * H + j];
      go += yv * W0[3 * H + j];
    }
    gi += bias[j]; gf += bias[H + j]; gg += bias[2 * H + j]; go += bias[3 * H + j];
    float cold = c[(long long)b * H + j];
    float cn = sigmoidf_(gf) * cold + sigmoidf_(gi) * tanhf_(gg);
    float hn = sigmoidf_(go) * tanhf_(cn);
    c[(long long)b * H + j] = cn;
    hout[(long long)b * H + j] = __float2half(hn);
  }
}

// ---- readout: y[b] = h4[b,:] . W_ro + b_ro ; also writes d_out[b*T + t] ----
__global__ __launch_bounds__(256) void k_readout(const __half* __restrict__ h4,
                                                 const float* __restrict__ Wro,
                                                 const float* __restrict__ bro,
                                                 float* __restrict__ y,
                                                 float* __restrict__ out, int tstep) {
  int wave = threadIdx.x >> 6, lane = threadIdx.x & 63;
  int b = blockIdx.x * 4 + wave;
  const __half2* hu = (const __half2*)(h4 + (long long)b * H) + lane * 8; // 16 halfs
  const float2* wp = (const float2*)Wro + lane * 8;
  float sum = 0.f;
#pragma unroll
  for (int s = 0; s < 8; s++) {
    float2 hf = __half22float2(hu[s]);
    float2 w = wp[s];
    sum += hf.x * w.x + hf.y * w.y;
  }
#pragma unroll
  for (int off = 32; off; off >>= 1) sum += __shfl_down(sum, off, 64);
  if (lane == 0) {
    float v = sum + bro[0];
    y[b] = v;
    out[(long long)b * T + tstep] = v;
  }
}

extern "C" void kernel_launch(void* const* d_in, const int* in_sizes, int n_in,
                              void* d_out, int out_size, void* d_ws, size_t ws_size,
                              hipStream_t stream) {
  const float* x    = (const float*)d_in[0];
  const float* Wih0 = (const float*)d_in[1];
  const float* Wxf  = (const float*)d_in[2]; // W_ih_rest (4,4096,1024)
  const float* Whf  = (const float*)d_in[3]; // W_hh (5,4096,1024)
  const float* bih  = (const float*)d_in[4];
  const float* bhh  = (const float*)d_in[5];
  const float* Wro  = (const float*)d_in[6];
  const float* bro  = (const float*)d_in[7];
  float* out = (float*)d_out;

  char* ws = (char*)d_ws;
  __half* Whb = (__half*)(ws);                   // 5*G*H fp16 = 41,943,040 B
  __half* Wxb = (__half*)(ws + 41943040LL);      // 4*G*H fp16 = 33,554,432 B
  __half* hA  = (__half*)(ws + 75497472LL);      // [LL][BS][H] fp16 buf0
  __half* hB  = (__half*)(ws + 80740352LL);      // buf1
  float*  c   = (float*)(ws + 85983232LL);       // [LL][BS][H] fp32
  float*  bias= (float*)(ws + 96468992LL);       // [LL][G]
  float*  y   = (float*)(ws + 96550912LL);       // [BS]

  k_convert<<<2048, 256, 0, stream>>>(Whf, Wxf, Whb, Wxb);
  k_bias_y<<<(LL * G + 255) / 256, 256, 0, stream>>>(bih, bhh, bias, y);
  k_init<<<(BS * H + 255) / 256, 256, 0, stream>>>(x, hA, c);

  dim3 cgrid(BS / 64, H / 32);
  for (int tst = 0; tst < T; ++tst) {
    __half* hin  = (tst & 1) ? hB : hA;
    __half* hout = (tst & 1) ? hA : hB;
    for (int l = 0; l < LL; l++) {
      const __half* Ah = hin + (long long)l * BS * H;
      const __half* Ax = (l == 0) ? nullptr : hout + (long long)(l - 1) * BS * H;
      const __half* Wh = Whb + (long long)l * G * H;
      const __half* Wx = (l == 0) ? nullptr : Wxb + (long long)(l - 1) * G * H;
      k_cell<<<cgrid, 256, 0, stream>>>(Ah, Ax, Wh, Wx, bias + l * G,
                                        (l == 0) ? Wih0 : nullptr,
                                        (l == 0) ? y : nullptr,
                                        c + (long long)l * BS * H,
                                        hout + (long long)l * BS * H);
    }
    k_readout<<<BS / 4, 256, 0, stream>>>(hout + (long long)(LL - 1) * BS * H,
                                          Wro, bro, y, out, tst);
  }
}

// Round 2
// 15900.151 us; speedup vs baseline: 1.2887x; 1.2887x over previous
//
#include <hip/hip_runtime.h>
#include <hip/hip_fp16.h>

#define LL 5
#define H 1024
#define G 4096   // 4*H
#define T 128
#define BS 512

#define BSH (512 * 1024)      // elements per layer of h/c
#define BSG (512 * 4096)      // elements per layer of gates
#define GH  (4096 * 1024)     // elements per weight matrix

typedef _Float16 f16x8 __attribute__((ext_vector_type(8)));
typedef float f32x4 __attribute__((ext_vector_type(4)));

__device__ __forceinline__ float sigmoidf_(float x) { return 1.f / (1.f + __expf(-x)); }
__device__ __forceinline__ float tanhf_(float x) { return 2.f / (1.f + __expf(-2.f * x)) - 1.f; }

// ================= prelude kernels =================

__global__ void k_convert(const float* __restrict__ Whf, const float* __restrict__ Wxf,
                          __half* __restrict__ Whb, __half* __restrict__ Wxb) {
  const long long n1 = (long long)LL * GH / 4;
  const long long n2 = (long long)(LL - 1) * GH / 4;
  long long i = (long long)blockIdx.x * blockDim.x + threadIdx.x;
  long long stride = (long long)gridDim.x * blockDim.x;
  for (long long v = i; v < n1 + n2; v += stride) {
    const float4* src; __half* dst; long long idx;
    if (v < n1) { src = (const float4*)Whf; dst = Whb; idx = v; }
    else        { src = (const float4*)Wxf; dst = Wxb; idx = v - n1; }
    float4 f = src[idx];
    ushort4 u;
    u.x = __half_as_ushort(__float2half(f.x));
    u.y = __half_as_ushort(__float2half(f.y));
    u.z = __half_as_ushort(__float2half(f.z));
    u.w = __half_as_ushort(__float2half(f.w));
    ((ushort4*)dst)[idx] = u;
  }
}

__global__ void k_bias_y(const float* __restrict__ bih, const float* __restrict__ bhh,
                         float* __restrict__ bias, float* __restrict__ y) {
  int i = blockIdx.x * blockDim.x + threadIdx.x;
  if (i < LL * G) bias[i] = bih[i] + bhh[i];
  if (i < BS) y[i] = 0.f;
}

__global__ void k_init(const float* __restrict__ x, __half* __restrict__ hbuf,
                       float* __restrict__ c) {
  int i = blockIdx.x * blockDim.x + threadIdx.x;
  if (i >= BS * H) return;
  float v = x[i];
  __half hb = __float2half(v);
  for (int l = 0; l < LL; l++) {
    hbuf[(long long)l * BSH + i] = hb;
    c[(long long)l * BSH + i] = v;
  }
}

// ================= GEMM core =================
// C(128 x 128) = A(128 x 1024) @ W_rows(128 of 4096 x 1024)^T
// Block tile: BM=128 batch rows, 32 jj-cols x 4 gates. 512 thr = 8 waves.
// Wave tile: 32 m x (4 gates x 16 jj). Fragment nt == gate -> all 4 gates per lane.
__device__ __forceinline__ void gemm_core(
    const __half* __restrict__ A, const __half* __restrict__ W,
    int m0, int jb, int t, __half (*As)[72], __half (*Bsh)[72], f32x4 acc[2][4])
{
  const int lane = t & 63, wave = t >> 6;
  const int quad = lane >> 4, col = lane & 15;
  const int wm = wave >> 1, wn = wave & 1;
  for (int it = 0; it < 16; ++it) {
    const int kb = it * 64;
#pragma unroll
    for (int s = 0; s < 2; s++) {
      int idx = s * 512 + t;
      int row = idx >> 3, cp = idx & 7;
      *(uint4*)(&As[row][cp * 8]) = *(const uint4*)(A + (row + m0) * H + kb + cp * 8);
    }
#pragma unroll
    for (int s = 0; s < 2; s++) {
      int idx = s * 512 + t;
      int row = idx >> 3, cp = idx & 7;
      int grow = (row >> 5) * H + jb + (row & 31);  // gate*H + j
      *(uint4*)(&Bsh[row][cp * 8]) = *(const uint4*)(W + grow * H + kb + cp * 8);
    }
    __syncthreads();
#pragma unroll
    for (int ks = 0; ks < 2; ks++) {
      f16x8 af[2], bfr[4];
#pragma unroll
      for (int mt = 0; mt < 2; mt++)
        af[mt] = *(const f16x8*)(&As[wm * 32 + mt * 16 + col][ks * 32 + quad * 8]);
#pragma unroll
      for (int nt = 0; nt < 4; nt++)
        bfr[nt] = *(const f16x8*)(&Bsh[nt * 32 + wn * 16 + col][ks * 32 + quad * 8]);
#pragma unroll
      for (int mt = 0; mt < 2; mt++)
#pragma unroll
        for (int nt = 0; nt < 4; nt++)
          acc[mt][nt] = __builtin_amdgcn_mfma_f32_16x16x32_f16(af[mt], bfr[nt], acc[mt][nt], 0, 0, 0);
    }
    __syncthreads();
  }
}

__device__ __forceinline__ void epilogue_cell(
    f32x4 acc[2][4], const __half* __restrict__ Ghin,
    float* __restrict__ c, __half* __restrict__ hout, int m0, int jb, int t)
{
  const int lane = t & 63, wave = t >> 6;
  const int quad = lane >> 4, col = lane & 15;
  const int wm = wave >> 1, wn = wave & 1;
  const int j = jb + wn * 16 + col;
#pragma unroll
  for (int mt = 0; mt < 2; mt++)
#pragma unroll
    for (int r = 0; r < 4; r++) {
      int b = m0 + wm * 32 + mt * 16 + quad * 4 + r;
      float gi = acc[mt][0][r] + __half2float(Ghin[b * G + j]);
      float gf = acc[mt][1][r] + __half2float(Ghin[b * G + H + j]);
      float gg = acc[mt][2][r] + __half2float(Ghin[b * G + 2 * H + j]);
      float go = acc[mt][3][r] + __half2float(Ghin[b * G + 3 * H + j]);
      float cold = c[b * H + j];
      float cn = sigmoidf_(gf) * cold + sigmoidf_(gi) * tanhf_(gg);
      c[b * H + j] = cn;
      hout[b * H + j] = __float2half(sigmoidf_(go) * tanhf_(cn));
    }
}

__device__ __forceinline__ void epilogue_store(
    f32x4 acc[2][4], __half* __restrict__ Ghout, const float* __restrict__ biasS,
    int m0, int jb, int t)
{
  const int lane = t & 63, wave = t >> 6;
  const int quad = lane >> 4, col = lane & 15;
  const int wm = wave >> 1, wn = wave & 1;
  const int j = jb + wn * 16 + col;
  float bs[4];
#pragma unroll
  for (int nt = 0; nt < 4; nt++) bs[nt] = biasS[nt * H + j];
#pragma unroll
  for (int mt = 0; mt < 2; mt++)
#pragma unroll
    for (int nt = 0; nt < 4; nt++)
#pragma unroll
      for (int r = 0; r < 4; r++) {
        int b = m0 + wm * 32 + mt * 16 + quad * 4 + r;
        Ghout[b * G + nt * H + j] = __float2half(acc[mt][nt][r] + bs[nt]);
      }
}

// ================= main-loop kernels =================

// z=0: cell for (t,l):  A=h[t][l-1], W=Wx[l], + Gh[t][l] -> c[l], h[t][l]
// z=1: store Gh[t+1][l-1]: A=h[t][l-1], W=Wh[l-1], +bias[l-1] -> Ghbuf[l-1]
__global__ __launch_bounds__(512) void k_dual(
    const __half* __restrict__ A, const __half* __restrict__ Wc,
    const __half* __restrict__ Ws, const __half* __restrict__ Ghin,
    __half* __restrict__ Ghout, const float* __restrict__ biasS,
    float* __restrict__ c, __half* __restrict__ hout)
{
  __shared__ __half As[128][72];
  __shared__ __half Bsh[128][72];
  const int t = threadIdx.x;
  const int jb = blockIdx.x * 32;
  const int m0 = blockIdx.y * 128;
  f32x4 acc[2][4];
#pragma unroll
  for (int a = 0; a < 2; a++)
#pragma unroll
    for (int b = 0; b < 4; b++) acc[a][b] = (f32x4){0.f, 0.f, 0.f, 0.f};
  if (blockIdx.z == 0) {
    gemm_core(A, Wc, m0, jb, t, As, Bsh, acc);
    epilogue_cell(acc, Ghin, c, hout, m0, jb, t);
  } else {
    gemm_core(A, Ws, m0, jb, t, As, Bsh, acc);
    epilogue_store(acc, Ghout, biasS, m0, jb, t);
  }
}

// Launch F: y<4 -> store Gh[t+1][4] (A=h[t][4], W=Wh[4]); y==4 -> readout(t)
__global__ __launch_bounds__(512) void k_store_ro(
    const __half* __restrict__ A, const __half* __restrict__ Ws,
    __half* __restrict__ Ghout, const float* __restrict__ biasS,
    const float* __restrict__ Wro, const float* __restrict__ bro,
    float* __restrict__ y, float* __restrict__ out, int tstep)
{
  __shared__ __half As[128][72];
  __shared__ __half Bsh[128][72];
  const int t = threadIdx.x;
  if (blockIdx.y < 4) {
    const int jb = blockIdx.x * 32;
    const int m0 = blockIdx.y * 128;
    f32x4 acc[2][4];
#pragma unroll
    for (int a = 0; a < 2; a++)
#pragma unroll
      for (int b = 0; b < 4; b++) acc[a][b] = (f32x4){0.f, 0.f, 0.f, 0.f};
    gemm_core(A, Ws, m0, jb, t, As, Bsh, acc);
    epilogue_store(acc, Ghout, biasS, m0, jb, t);
  } else {
    const int lane = t & 63, wave = t >> 6;
#pragma unroll
    for (int rr = 0; rr < 2; rr++) {
      int row = blockIdx.x * 16 + wave * 2 + rr;
      const __half2* p = (const __half2*)(A + row * H) + lane * 8;
      const float2* wp = (const float2*)Wro + lane * 8;
      float sum = 0.f;
#pragma unroll
      for (int s = 0; s < 8; s++) {
        float2 hf = __half22float2(p[s]);
        float2 w = wp[s];
        sum += hf.x * w.x + hf.y * w.y;
      }
#pragma unroll
      for (int off = 32; off; off >>= 1) sum += __shfl_down(sum, off, 64);
      if (lane == 0) {
        float v = sum + bro[0];
        y[row] = v;
        out[row * T + tstep] = v;
      }
    }
  }
}

// prelude: Gh[0][l] = fp16(x) @ Wh[l]^T + bias[l], for l = blockIdx.z
__global__ __launch_bounds__(512) void k_init_gh(
    const __half* __restrict__ A, const __half* __restrict__ WhbBase,
    __half* __restrict__ GhBase, const float* __restrict__ biasBase)
{
  __shared__ __half As[128][72];
  __shared__ __half Bsh[128][72];
  const int t = threadIdx.x;
  const int jb = blockIdx.x * 32;
  const int m0 = blockIdx.y * 128;
  const int l = blockIdx.z;
  f32x4 acc[2][4];
#pragma unroll
  for (int a = 0; a < 2; a++)
#pragma unroll
    for (int b = 0; b < 4; b++) acc[a][b] = (f32x4){0.f, 0.f, 0.f, 0.f};
  gemm_core(A, WhbBase + (long long)l * GH, m0, jb, t, As, Bsh, acc);
  epilogue_store(acc, GhBase + (long long)l * BSG, biasBase + l * G, m0, jb, t);
}

// cell finalize for layer 0: gates = Gh[t][0] (has bias) + y[t-1]*W_ih0
__global__ __launch_bounds__(256) void k_fin0(
    const __half* __restrict__ Gh0, const float* __restrict__ y,
    const float* __restrict__ W0, float* __restrict__ c0, __half* __restrict__ h0out)
{
  int i = blockIdx.x * blockDim.x + threadIdx.x;
  if (i >= BS * H) return;
  int b = i >> 10, j = i & 1023;
  float yv = y[b];
  float gi = __half2float(Gh0[b * G + j]) + yv * W0[j];
  float gf = __half2float(Gh0[b * G + H + j]) + yv * W0[H + j];
  float gg = __half2float(Gh0[b * G + 2 * H + j]) + yv * W0[2 * H + j];
  float go = __half2float(Gh0[b * G + 3 * H + j]) + yv * W0[3 * H + j];
  float cold = c0[i];
  float cn = sigmoidf_(gf) * cold + sigmoidf_(gi) * tanhf_(gg);
  c0[i] = cn;
  h0out[i] = __float2half(sigmoidf_(go) * tanhf_(cn));
}

extern "C" void kernel_launch(void* const* d_in, const int* in_sizes, int n_in,
                              void* d_out, int out_size, void* d_ws, size_t ws_size,
                              hipStream_t stream) {
  const float* x    = (const float*)d_in[0];
  const float* Wih0 = (const float*)d_in[1];
  const float* Wxf  = (const float*)d_in[2];
  const float* Whf  = (const float*)d_in[3];
  const float* bih  = (const float*)d_in[4];
  const float* bhh  = (const float*)d_in[5];
  const float* Wro  = (const float*)d_in[6];
  const float* bro  = (const float*)d_in[7];
  float* out = (float*)d_out;

  char* ws = (char*)d_ws;
  __half* Whb  = (__half*)(ws);                     // 41,943,040 B
  __half* Wxb  = (__half*)(ws + 41943040LL);        // 33,554,432 B
  __half* hbuf = (__half*)(ws + 75497472LL);        // 5,242,880 B
  float*  c    = (float*)(ws + 80740352LL);         // 10,485,760 B
  __half* Ghb  = (__half*)(ws + 91226112LL);        // 20,971,520 B
  float*  bias = (float*)(ws + 112197632LL);        // 81,920 B
  float*  y    = (float*)(ws + 112279552LL);        // 2,048 B

  k_convert<<<2048, 256, 0, stream>>>(Whf, Wxf, Whb, Wxb);
  k_bias_y<<<(LL * G + 255) / 256, 256, 0, stream>>>(bih, bhh, bias, y);
  k_init<<<(BS * H + 255) / 256, 256, 0, stream>>>(x, hbuf, c);
  k_init_gh<<<dim3(32, 4, 5), 512, 0, stream>>>(hbuf, Whb, Ghb, bias);

  for (int tst = 0; tst < T; ++tst) {
    k_fin0<<<2048, 256, 0, stream>>>(Ghb, y, Wih0, c, hbuf);
    for (int l = 1; l < LL; l++) {
      k_dual<<<dim3(32, 4, 2), 512, 0, stream>>>(
          hbuf + (long long)(l - 1) * BSH,
          Wxb + (long long)(l - 1) * GH,
          Whb + (long long)(l - 1) * GH,
          Ghb + (long long)l * BSG,
          Ghb + (long long)(l - 1) * BSG,
          bias + (l - 1) * G,
          c + (long long)l * BSH,
          hbuf + (long long)l * BSH);
    }
    k_store_ro<<<dim3(32, 5), 512, 0, stream>>>(
        hbuf + 4LL * BSH, Whb + 4LL * GH, Ghb + 4LL * BSG, bias + 4 * G,
        Wro, bro, y, out, tst);
  }
}

// Round 3
// 9130.177 us; speedup vs baseline: 2.2442x; 1.7415x over previous
//
#include <hip/hip_runtime.h>
#include <hip/hip_fp16.h>

#define LL 5
#define H 1024
#define G 4096   // 4*H
#define T 128
#define BS 512
#define BSH (BS * H)
#define BSG (BS * G)
#define GH  (G * H)

typedef _Float16 f16x8 __attribute__((ext_vector_type(8)));
typedef float f32x4 __attribute__((ext_vector_type(4)));

__device__ __forceinline__ float sigmoidf_(float x) { return 1.f / (1.f + __expf(-x)); }
__device__ __forceinline__ float tanhf_(float x) { return 2.f / (1.f + __expf(-2.f * x)) - 1.f; }

// async 16B global->LDS (DMA, no VGPR roundtrip). LDS dest = wave-uniform base + lane*16.
__device__ __forceinline__ void gll16(const void* g, void* l) {
  __builtin_amdgcn_global_load_lds(
      (const __attribute__((address_space(1))) void*)g,
      (__attribute__((address_space(3))) void*)l, 16, 0, 0);
}

// ================= prelude kernels =================

__global__ void k_convert(const float* __restrict__ Whf, const float* __restrict__ Wxf,
                          __half* __restrict__ Whb, __half* __restrict__ Wxb) {
  const long long n1 = (long long)LL * GH / 4;
  const long long n2 = (long long)(LL - 1) * GH / 4;
  long long i = (long long)blockIdx.x * blockDim.x + threadIdx.x;
  long long stride = (long long)gridDim.x * blockDim.x;
  for (long long v = i; v < n1 + n2; v += stride) {
    const float4* src; __half* dst; long long idx;
    if (v < n1) { src = (const float4*)Whf; dst = Whb; idx = v; }
    else        { src = (const float4*)Wxf; dst = Wxb; idx = v - n1; }
    float4 f = src[idx];
    ushort4 u;
    u.x = __half_as_ushort(__float2half(f.x));
    u.y = __half_as_ushort(__float2half(f.y));
    u.z = __half_as_ushort(__float2half(f.z));
    u.w = __half_as_ushort(__float2half(f.w));
    ((ushort4*)dst)[idx] = u;
  }
}

__global__ void k_bias_y(const float* __restrict__ bih, const float* __restrict__ bhh,
                         float* __restrict__ bias, float* __restrict__ y0,
                         float* __restrict__ y1) {
  int i = blockIdx.x * blockDim.x + threadIdx.x;
  if (i < LL * G) bias[i] = bih[i] + bhh[i];
  if (i < BS) { y0[i] = 0.f; y1[i] = 0.f; }
}

__global__ void k_init(const float* __restrict__ x, __half* __restrict__ hbuf,
                       float* __restrict__ c) {
  int i = blockIdx.x * blockDim.x + threadIdx.x;
  if (i >= BS * H) return;
  float v = x[i];
  __half hb = __float2half(v);
  for (int l = 0; l < LL; l++) {
    hbuf[(long long)l * BSH + i] = hb;
    c[(long long)l * BSH + i] = v;
  }
}

// ================= GEMM core (async, dbuf, XOR-swizzled LDS) =================
// C(64 x 128) = A(64 rows x K=1024) @ W(128 rows x 1024)^T, W rows = 4 gates x 32 j.
// 256 threads = 4 waves; wave tile 32m x 64n; nt == gate so each lane holds i,f,g,o.
// LDS: 2 x (A 4096 halfs + B 8192 halfs) = 48 KB. Chunk (16B=8 halfs) at slot
// s within row r holds global chunk s ^ (r&7)  -> frag reads are 2-way max (free).

#define SH_HALFS 24576

__device__ __forceinline__ void stage_tile(const __half* __restrict__ A,
                                           const __half* __restrict__ W,
                                           int m0, int jb, int kb,
                                           __half* aB, __half* bB,
                                           int wave, int lane) {
  const int i8 = lane >> 3;          // row within 8-row group
  const int j8 = lane & 7;           // LDS slot chunk within row
  const int kch = j8 ^ i8;           // swizzled source chunk
#pragma unroll
  for (int s = 0; s < 2; s++) {      // A: 8 calls of 8 rows, this wave does 2
    int c = wave * 2 + s;
    int row = c * 8 + i8;
    gll16(A + (m0 + row) * H + kb + kch * 8, aB + c * 512);
  }
#pragma unroll
  for (int s = 0; s < 4; s++) {      // B: 16 calls of 8 rows, this wave does 4
    int c = wave * 4 + s;
    int row = c * 8 + i8;                          // 0..127
    int grow = (row >> 5) * H + jb + (row & 31);   // gate*H + j
    gll16(W + grow * H + kb + kch * 8, bB + c * 512);
  }
}

__device__ __forceinline__ void compute_tile(const __half* aB, const __half* bB,
                                             int wave, int lane, f32x4 acc[2][4]) {
  const int quad = lane >> 4, col = lane & 15;
  const int wm = wave >> 1, wn = wave & 1;
  const int sw = col & 7;
#pragma unroll
  for (int ks = 0; ks < 2; ks++) {
    const int kc = ks * 4 + quad;
    const int kcs = kc ^ sw;
    f16x8 af[2], bf[4];
#pragma unroll
    for (int mt = 0; mt < 2; mt++) {
      int r = wm * 32 + mt * 16 + col;
      af[mt] = *(const f16x8*)(aB + ((r << 3) + kcs) * 8);
    }
#pragma unroll
    for (int nt = 0; nt < 4; nt++) {
      int n = nt * 32 + wn * 16 + col;
      bf[nt] = *(const f16x8*)(bB + ((n << 3) + kcs) * 8);
    }
#pragma unroll
    for (int mt = 0; mt < 2; mt++)
#pragma unroll
      for (int nt = 0; nt < 4; nt++)
        acc[mt][nt] = __builtin_amdgcn_mfma_f32_16x16x32_f16(af[mt], bf[nt], acc[mt][nt], 0, 0, 0);
  }
}

__device__ __forceinline__ void gemm_async(const __half* __restrict__ A,
                                           const __half* __restrict__ W,
                                           int m0, int jb, __half* sh, int t,
                                           f32x4 acc[2][4]) {
  const int wave = t >> 6, lane = t & 63;
  stage_tile(A, W, m0, jb, 0, sh, sh + 4096, wave, lane);
  for (int it = 0; it < 16; ++it) {
    __syncthreads();  // drains vmcnt(0): buf[it&1] ready; prev reads of other buf done
    const int cur = it & 1;
    if (it < 15)
      stage_tile(A, W, m0, jb, (it + 1) * 64,
                 sh + (cur ? 0 : 12288), sh + (cur ? 4096 : 16384), wave, lane);
    compute_tile(sh + (cur ? 12288 : 0), sh + (cur ? 16384 : 4096), wave, lane, acc);
  }
}

__device__ __forceinline__ void epilogue_store(f32x4 acc[2][4], __half* __restrict__ Ghout,
                                               const float* __restrict__ biasS,
                                               int m0, int jb, int t) {
  const int lane = t & 63, wave = t >> 6;
  const int quad = lane >> 4, col = lane & 15;
  const int wm = wave >> 1, wn = wave & 1;
  const int j = jb + wn * 16 + col;
  float bs[4];
#pragma unroll
  for (int nt = 0; nt < 4; nt++) bs[nt] = biasS[nt * H + j];
#pragma unroll
  for (int mt = 0; mt < 2; mt++)
#pragma unroll
    for (int nt = 0; nt < 4; nt++)
#pragma unroll
      for (int r = 0; r < 4; r++) {
        int b = m0 + wm * 32 + mt * 16 + quad * 4 + r;
        Ghout[b * G + nt * H + j] = __float2half(acc[mt][nt][r] + bs[nt]);
      }
}

__device__ __forceinline__ void epilogue_cell(f32x4 acc[2][4],
                                              const __half* __restrict__ Ghin,
                                              float* __restrict__ c, __half* __restrict__ hout,
                                              int m0, int jb, int t,
                                              const float* __restrict__ Wro,
                                              float* __restrict__ yAcc, float* red) {
  const int lane = t & 63, wave = t >> 6;
  const int quad = lane >> 4, col = lane & 15;
  const int wm = wave >> 1, wn = wave & 1;
  const int j = jb + wn * 16 + col;
  const float wj = Wro ? Wro[j] : 0.f;
#pragma unroll
  for (int mt = 0; mt < 2; mt++)
#pragma unroll
    for (int r = 0; r < 4; r++) {
      int row = wm * 32 + mt * 16 + quad * 4 + r;
      int b = m0 + row;
      float gi = acc[mt][0][r] + __half2float(Ghin[b * G + j]);
      float gf = acc[mt][1][r] + __half2float(Ghin[b * G + H + j]);
      float gg = acc[mt][2][r] + __half2float(Ghin[b * G + 2 * H + j]);
      float go = acc[mt][3][r] + __half2float(Ghin[b * G + 3 * H + j]);
      float cold = c[b * H + j];
      float cn = sigmoidf_(gf) * cold + sigmoidf_(gi) * tanhf_(gg);
      float hn = sigmoidf_(go) * tanhf_(cn);
      c[b * H + j] = cn;
      hout[b * H + j] = __float2half(hn);
      if (Wro) red[row * 33 + wn * 16 + col] = hn * wj;
    }
  if (Wro) {  // block-level readout reduction: 32 j-columns -> 1 atomic per row
    __syncthreads();
    if (t < 64) {
      float s = 0.f;
#pragma unroll
      for (int k = 0; k < 32; k++) s += red[t * 33 + k];
      atomicAdd(yAcc + m0 + t, s);
    }
  }
}

// ================= main-loop kernels =================

// z=0: x-GEMM + cell for (t,l): A @ Wc + Ghin -> c, hout  (l==4 also: readout into yAcc)
// z=1: h-GEMM: A @ Ws + biasS -> Ghout   (Gh[t+1][l-1])
// z=2 (only l==2 launch): A2 @ Ws2 + bias2 -> Gh2  (Gh[t][4] from h[t-1][4])
__global__ __launch_bounds__(256) void k_dual(
    const __half* __restrict__ A, const __half* __restrict__ Wc,
    const __half* __restrict__ Ws, const __half* __restrict__ Ghin,
    __half* __restrict__ Ghout, const float* __restrict__ biasS,
    float* __restrict__ c_, __half* __restrict__ hout,
    const float* __restrict__ Wro, float* __restrict__ yAcc,
    const __half* __restrict__ A2, const __half* __restrict__ Ws2,
    __half* __restrict__ Gh2, const float* __restrict__ bias2)
{
  __shared__ __half sh[SH_HALFS];
  const int t = threadIdx.x;
  const int jb = blockIdx.x * 32;
  const int m0 = blockIdx.y * 64;
  f32x4 acc[2][4];
#pragma unroll
  for (int a = 0; a < 2; a++)
#pragma unroll
    for (int b = 0; b < 4; b++) acc[a][b] = (f32x4){0.f, 0.f, 0.f, 0.f};
  if (blockIdx.z == 0) {
    gemm_async(A, Wc, m0, jb, sh, t, acc);
    epilogue_cell(acc, Ghin, c_, hout, m0, jb, t, Wro, yAcc, (float*)sh);
  } else if (blockIdx.z == 1) {
    gemm_async(A, Ws, m0, jb, sh, t, acc);
    epilogue_store(acc, Ghout, biasS, m0, jb, t);
  } else {
    gemm_async(A2, Ws2, m0, jb, sh, t, acc);
    epilogue_store(acc, Gh2, bias2, m0, jb, t);
  }
}

// HEAD: pure elementwise layer-0 cell finalize + y bookkeeping (fast chain link)
__global__ __launch_bounds__(256) void k_head(
    const __half* __restrict__ Gh0, const float* __restrict__ W0,
    const float* __restrict__ yA, float* __restrict__ yB,
    const float* __restrict__ bro, float* __restrict__ c0,
    __half* __restrict__ h0, float* __restrict__ out, int tPrev)
{
  int tid = blockIdx.x * 256 + threadIdx.x;   // 128 blocks -> 32768 threads
  for (int e4 = tid; e4 < BS * (H / 4); e4 += 32768) {
    int b = e4 >> 8;
    int j = (e4 & 255) << 2;
    float yv = yA[b];
    const __half2* p;
    p = (const __half2*)(Gh0 + b * G + j);
    float2 i01 = __half22float2(p[0]), i23 = __half22float2(p[1]);
    p = (const __half2*)(Gh0 + b * G + H + j);
    float2 f01 = __half22float2(p[0]), f23 = __half22float2(p[1]);
    p = (const __half2*)(Gh0 + b * G + 2 * H + j);
    float2 g01 = __half22float2(p[0]), g23 = __half22float2(p[1]);
    p = (const __half2*)(Gh0 + b * G + 3 * H + j);
    float2 o01 = __half22float2(p[0]), o23 = __half22float2(p[1]);
    float4 wi = *(const float4*)(W0 + j);
    float4 wf = *(const float4*)(W0 + H + j);
    float4 wg = *(const float4*)(W0 + 2 * H + j);
    float4 wo = *(const float4*)(W0 + 3 * H + j);
    float4 cc = *(const float4*)(c0 + b * H + j);
    float gi[4] = {i01.x + yv * wi.x, i01.y + yv * wi.y, i23.x + yv * wi.z, i23.y + yv * wi.w};
    float gf[4] = {f01.x + yv * wf.x, f01.y + yv * wf.y, f23.x + yv * wf.z, f23.y + yv * wf.w};
    float gg[4] = {g01.x + yv * wg.x, g01.y + yv * wg.y, g23.x + yv * wg.z, g23.y + yv * wg.w};
    float go[4] = {o01.x + yv * wo.x, o01.y + yv * wo.y, o23.x + yv * wo.z, o23.y + yv * wo.w};
    float cold[4] = {cc.x, cc.y, cc.z, cc.w};
    float cn[4], hn[4];
#pragma unroll
    for (int k = 0; k < 4; k++) {
      cn[k] = sigmoidf_(gf[k]) * cold[k] + sigmoidf_(gi[k]) * tanhf_(gg[k]);
      hn[k] = sigmoidf_(go[k]) * tanhf_(cn[k]);
    }
    *(float4*)(c0 + b * H + j) = (float4){cn[0], cn[1], cn[2], cn[3]};
    ushort4 hv;
    hv.x = __half_as_ushort(__float2half(hn[0]));
    hv.y = __half_as_ushort(__float2half(hn[1]));
    hv.z = __half_as_ushort(__float2half(hn[2]));
    hv.w = __half_as_ushort(__float2half(hn[3]));
    *(ushort4*)(h0 + b * H + j) = hv;
    if (j == 0) {
      if (tPrev >= 0) out[b * T + tPrev] = yv;
      yB[b] = bro[0];   // re-init accumulator for this step's fused readout
    }
  }
}

// prelude: Gh[0][l] = fp16(x) @ Wh[l]^T + bias[l], l = 0..3 (l=4 done by dual(l=2,t=0))
__global__ __launch_bounds__(256) void k_init_gh(
    const __half* __restrict__ hb, const __half* __restrict__ WhbBase,
    __half* __restrict__ GhBase, const float* __restrict__ biasBase)
{
  __shared__ __half sh[SH_HALFS];
  const int t = threadIdx.x;
  const int jb = blockIdx.x * 32;
  const int m0 = blockIdx.y * 64;
  const int l = blockIdx.z;
  f32x4 acc[2][4];
#pragma unroll
  for (int a = 0; a < 2; a++)
#pragma unroll
    for (int b = 0; b < 4; b++) acc[a][b] = (f32x4){0.f, 0.f, 0.f, 0.f};
  gemm_async(hb + l * BSH, WhbBase + (long long)l * GH, m0, jb, sh, t, acc);
  epilogue_store(acc, GhBase + (long long)l * BSG, biasBase + l * G, m0, jb, t);
}

__global__ void k_tail(const float* __restrict__ yF, float* __restrict__ out) {
  int b = threadIdx.x + blockIdx.x * blockDim.x;
  if (b < BS) out[b * T + (T - 1)] = yF[b];
}

extern "C" void kernel_launch(void* const* d_in, const int* in_sizes, int n_in,
                              void* d_out, int out_size, void* d_ws, size_t ws_size,
                              hipStream_t stream) {
  const float* x    = (const float*)d_in[0];
  const float* Wih0 = (const float*)d_in[1];
  const float* Wxf  = (const float*)d_in[2];
  const float* Whf  = (const float*)d_in[3];
  const float* bih  = (const float*)d_in[4];
  const float* bhh  = (const float*)d_in[5];
  const float* Wro  = (const float*)d_in[6];
  const float* bro  = (const float*)d_in[7];
  float* out = (float*)d_out;

  char* ws = (char*)d_ws;
  __half* Whb  = (__half*)(ws);                     // 41,943,040 B
  __half* Wxb  = (__half*)(ws + 41943040LL);        // 33,554,432 B
  __half* hbuf = (__half*)(ws + 75497472LL);        // 5,242,880 B
  float*  c    = (float*)(ws + 80740352LL);         // 10,485,760 B
  __half* Ghb  = (__half*)(ws + 91226112LL);        // 20,971,520 B
  float*  bias = (float*)(ws + 112197632LL);        // 81,920 B
  float*  y0   = (float*)(ws + 112279552LL);        // 2,048 B
  float*  y1   = (float*)(ws + 112281600LL);        // 2,048 B

  k_convert<<<2048, 256, 0, stream>>>(Whf, Wxf, Whb, Wxb);
  k_bias_y<<<80, 256, 0, stream>>>(bih, bhh, bias, y0, y1);
  k_init<<<2048, 256, 0, stream>>>(x, hbuf, c);
  k_init_gh<<<dim3(32, 8, 4), 256, 0, stream>>>(hbuf, Whb, Ghb, bias);

  for (int tst = 0; tst < T; ++tst) {
    float* yA = (tst & 1) ? y1 : y0;
    float* yB = (tst & 1) ? y0 : y1;
    k_head<<<128, 256, 0, stream>>>(Ghb, Wih0, yA, yB, bro, c, hbuf, out, tst - 1);
    for (int l = 1; l < LL; l++) {
      dim3 grid(32, 8, (l == 2) ? 3 : 2);
      k_dual<<<grid, 256, 0, stream>>>(
          hbuf + (l - 1) * BSH,
          Wxb + (long long)(l - 1) * GH,
          Whb + (long long)(l - 1) * GH,
          Ghb + l * BSG,
          Ghb + (l - 1) * BSG,
          bias + (l - 1) * G,
          c + l * BSH,
          hbuf + l * BSH,
          (l == 4) ? Wro : nullptr,
          (l == 4) ? yB : nullptr,
          hbuf + 4 * BSH,            // A2: h[t-1][4] (only used when z==2)
          Whb + 4LL * GH,
          Ghb + 4 * BSG,
          bias + 4 * G);
    }
  }
  k_tail<<<1, 512, 0, stream>>>(y0, out);  // y[127] accumulated into y0 (t=127 -> yB=y0)
}